// Round 5
// baseline (343.520 us; speedup 1.0000x reference)
//
#include <hip/hip_runtime.h>
#include <cstdint>
#include <cstddef>
#include <cfloat>
#include <climits>

#define D_DIM   1024
#define P_DIM   2048
#define NB      2
#define NR      128
#define NS      128
#define KTOP    4
#define E_DIM   8192
#define ANG_EPS 1e-8f
#define M_PAIR  768   // 128 ref_t + 128 ref_s + 512 H rows
#define N_PAIR  768   // 3 pairs * (128 Sh_t + 128 Sh_s)

#define SIM_SLICES  4
#define SIM_KSLICE  256     // K per block; 8 chunks of 32
#define PAIR_SLICES 4
#define PAIR_KSLICE 256
#define PAIR_STAGES 16

#define TOPK_DELTA  1.0f    // candidate window below 4th approx score (>>20 sigma of bf16 error)
#define MAXCAND     128

typedef short short8 __attribute__((ext_vector_type(8)));
typedef float f32x4 __attribute__((ext_vector_type(4)));

__device__ __forceinline__ float dot4(float4 a, float4 b) {
  return a.x * b.x + a.y * b.y + a.z * b.z + a.w * b.w;
}

__device__ __forceinline__ float huber(float e) {
  float ae = fabsf(e);
  return ae <= 1.0f ? 0.5f * e * e : ae - 0.5f;
}

__device__ __forceinline__ bool better(float va, int ia, float vb, int ib) {
  return (va > vb) || (va == vb && ia < ib);
}

// RNE float -> bf16 bits
__device__ __forceinline__ unsigned int f2bf(float x) {
  union { float f; unsigned int u; } v; v.f = x;
  unsigned int r = v.u + 0x7fffu + ((v.u >> 16) & 1u);
  return r >> 16;
}
__device__ __forceinline__ unsigned int pk2bf(float x, float y) {
  return f2bf(x) | (f2bf(y) << 16);
}

// valid result on thread 0 only; scratch must hold blockDim/64 floats
__device__ __forceinline__ float block_reduce_sum(float v, float* scratch) {
  #pragma unroll
  for (int o = 32; o > 0; o >>= 1) v += __shfl_down(v, o);
  __syncthreads();
  if ((threadIdx.x & 63) == 0) scratch[threadIdx.x >> 6] = v;
  __syncthreads();
  float r = 0.0f;
  int nw = (int)(blockDim.x >> 6);
  if ((int)threadIdx.x < nw) r = scratch[threadIdx.x];
  #pragma unroll
  for (int o = 2; o > 0; o >>= 1) r += __shfl_down(r, o);
  return r;
}

// ============ sim GEMM via bf16 MFMA: 128(M)x128(N) tile, split-K 4, fused fp32 norms ============
// fp32 VALU sim plateaued at ~75us (near the 103 TF practical fp32 ceiling). bf16 MFMA
// makes this HBM-bound; approximate scores are fixed up by an exact fp32 recheck in topk.
__global__ __launch_bounds__(256) void sim_gemm_kernel(const float* __restrict__ tf,
                                                       const int* __restrict__ ref_perm,
                                                       float* __restrict__ simP,
                                                       float* __restrict__ bn2P) {
  __shared__ unsigned int Ah[128 * 20];   // 128 rows x 40 bf16 (32 used + pad) = 80 B/row
  __shared__ unsigned int Bh[128 * 20];
  __shared__ const float* Arow[128];
  __shared__ const float* Brow[128];
  const int tid = threadIdx.x;
  const int b = blockIdx.z;
  const int slice = blockIdx.y;
  const int nbase = blockIdx.x * 128;
  const int kbase = slice * SIM_KSLICE;
  if (tid < 128) {
    Arow[tid] = tf + ((size_t)(b * 8) * P_DIM + ref_perm[tid]) * D_DIM + kbase;
  } else {
    int n = nbase + (tid - 128);
    Brow[tid - 128] = tf + ((size_t)(b * 8 + 1 + 2 * (n >> 11)) * P_DIM + (n & (P_DIM - 1))) * D_DIM + kbase;
  }
  __syncthreads();

  const int srow = tid >> 1;          // staging row 0..127
  const int shalf = (tid & 1) * 16;   // k-offset 0 or 16
  const float* asrc = Arow[srow] + shalf;
  const float* bsrc = Brow[srow] + shalf;

  float4 av[4], bv[4];
  #pragma unroll
  for (int i = 0; i < 4; ++i) {
    av[i] = *(const float4*)(asrc + 4 * i);
    bv[i] = *(const float4*)(bsrc + 4 * i);
  }

  const int wave = tid >> 6;
  const int lane = tid & 63;
  const int fr = lane & 15;           // fragment row/col within 16
  const int q16 = (lane >> 4) * 16;   // byte offset of k-group
  const char* Ab = (const char*)Ah;
  const char* Bb = (const char*)Bh;

  f32x4 acc[2][8];
  #pragma unroll
  for (int mt = 0; mt < 2; ++mt)
    #pragma unroll
    for (int nt = 0; nt < 8; ++nt)
      #pragma unroll
      for (int r = 0; r < 4; ++r) acc[mt][nt][r] = 0.0f;

  float bn2 = 0.0f;
  unsigned int* adst = Ah + srow * 20 + (tid & 1) * 8;
  unsigned int* bdst = Bh + srow * 20 + (tid & 1) * 8;

  for (int ck = 0; ck < 8; ++ck) {
    // fp32-exact norm partials (pre-conversion values)
    bn2 += dot4(bv[0], bv[0]) + dot4(bv[1], bv[1]) + dot4(bv[2], bv[2]) + dot4(bv[3], bv[3]);
    unsigned int ua[8], ub[8];
    #pragma unroll
    for (int i = 0; i < 4; ++i) {
      ua[2 * i]     = pk2bf(av[i].x, av[i].y);
      ua[2 * i + 1] = pk2bf(av[i].z, av[i].w);
      ub[2 * i]     = pk2bf(bv[i].x, bv[i].y);
      ub[2 * i + 1] = pk2bf(bv[i].z, bv[i].w);
    }
    __syncthreads();   // prior chunk's fragment reads complete
    *(uint4*)(adst)     = make_uint4(ua[0], ua[1], ua[2], ua[3]);
    *(uint4*)(adst + 4) = make_uint4(ua[4], ua[5], ua[6], ua[7]);
    *(uint4*)(bdst)     = make_uint4(ub[0], ub[1], ub[2], ub[3]);
    *(uint4*)(bdst + 4) = make_uint4(ub[4], ub[5], ub[6], ub[7]);
    __syncthreads();
    if (ck < 7) {   // prefetch next chunk while MFMAs run
      const float* an = asrc + (ck + 1) * 32;
      const float* bn = bsrc + (ck + 1) * 32;
      #pragma unroll
      for (int i = 0; i < 4; ++i) {
        av[i] = *(const float4*)(an + 4 * i);
        bv[i] = *(const float4*)(bn + 4 * i);
      }
    }
    short8 afr[2], bfr[8];
    #pragma unroll
    for (int mt = 0; mt < 2; ++mt)
      afr[mt] = *(const short8*)(Ab + (wave * 32 + mt * 16 + fr) * 80 + q16);
    #pragma unroll
    for (int nt = 0; nt < 8; ++nt)
      bfr[nt] = *(const short8*)(Bb + (nt * 16 + fr) * 80 + q16);
    #pragma unroll
    for (int mt = 0; mt < 2; ++mt)
      #pragma unroll
      for (int nt = 0; nt < 8; ++nt)
        acc[mt][nt] = __builtin_amdgcn_mfma_f32_16x16x32_bf16(afr[mt], bfr[nt], acc[mt][nt], 0, 0, 0);
  }

  // norms: combine the two k-halves (threads t, t^1 share a row)
  bn2 += __shfl_xor(bn2, 1);
  if ((tid & 1) == 0)
    bn2P[((size_t)slice * NB + b) * E_DIM + nbase + srow] = bn2;

  // C/D layout: col = lane&15, row = (lane>>4)*4 + reg  [m89-verified]
  float* base = simP + (((size_t)slice * NB + b) * NR) * E_DIM + nbase;
  const int crow = (lane >> 4) * 4;
  #pragma unroll
  for (int mt = 0; mt < 2; ++mt) {
    #pragma unroll
    for (int nt = 0; nt < 8; ++nt) {
      int col = nt * 16 + fr;
      #pragma unroll
      for (int r = 0; r < 4; ++r) {
        int m = wave * 32 + mt * 16 + crow + r;
        base[(size_t)m * E_DIM + col] = acc[mt][nt][r];
      }
    }
  }
}

// ---------- top-4 per row: approx (bf16) scores -> candidate window -> exact fp32 recheck ----------
__global__ __launch_bounds__(256) void topk_kernel(const float* __restrict__ simP,
                                                   const float* __restrict__ bn2P,
                                                   const float* __restrict__ tf,
                                                   const int* __restrict__ ref_perm,
                                                   int* __restrict__ tki) {
  __shared__ float scores[E_DIM];       // 32 KB
  __shared__ float sv[1024];
  __shared__ int si[1024];
  __shared__ float candVal[MAXCAND];
  __shared__ int candIdx[MAXCAND];
  __shared__ int cnt;
  const int tid = threadIdx.x;
  const int br = blockIdx.x;
  const int b = br >> 7;
  const int r = br & 127;
  const size_t ST = (size_t)NB * NR * E_DIM;
  const size_t SN = (size_t)NB * E_DIM;
  const float* p = simP + (size_t)br * E_DIM;
  const float* q = bn2P + (size_t)b * E_DIM;
  if (tid == 0) cnt = 0;

  float tv[4] = {-FLT_MAX, -FLT_MAX, -FLT_MAX, -FLT_MAX};
  int ti[4] = {INT_MAX, INT_MAX, INT_MAX, INT_MAX};
  for (int e4 = tid * 4; e4 < E_DIM; e4 += 1024) {
    float4 s = *(const float4*)(p + e4);
    float4 s1 = *(const float4*)(p + ST + e4);
    float4 s2 = *(const float4*)(p + 2 * ST + e4);
    float4 s3 = *(const float4*)(p + 3 * ST + e4);
    float4 n0 = *(const float4*)(q + e4);
    float4 n1 = *(const float4*)(q + SN + e4);
    float4 n2 = *(const float4*)(q + 2 * SN + e4);
    float4 n3 = *(const float4*)(q + 3 * SN + e4);
    float sj[4] = {s.x + s1.x + s2.x + s3.x, s.y + s1.y + s2.y + s3.y,
                   s.z + s1.z + s2.z + s3.z, s.w + s1.w + s2.w + s3.w};
    float nj[4] = {n0.x + n1.x + n2.x + n3.x, n0.y + n1.y + n2.y + n3.y,
                   n0.z + n1.z + n2.z + n3.z, n0.w + n1.w + n2.w + n3.w};
    #pragma unroll
    for (int j = 0; j < 4; ++j) {
      int e = e4 + j;
      float x = sj[j] * rsqrtf(fmaxf(nj[j], 1e-24f));
      scores[e] = x;
      if (better(x, e, tv[3], ti[3])) {
        tv[3] = x; ti[3] = e;
        #pragma unroll
        for (int k = 3; k > 0; --k) {
          if (better(tv[k], ti[k], tv[k - 1], ti[k - 1])) {
            float fv = tv[k]; tv[k] = tv[k - 1]; tv[k - 1] = fv;
            int fi2 = ti[k]; ti[k] = ti[k - 1]; ti[k - 1] = fi2;
          }
        }
      }
    }
  }
  #pragma unroll
  for (int k = 0; k < 4; ++k) { sv[tid * 4 + k] = tv[k]; si[tid * 4 + k] = ti[k]; }
  for (int stride = 128; stride > 0; stride >>= 1) {
    __syncthreads();
    if (tid < stride) {
      float av[4], bv2[4]; int ai[4], bi2[4];
      #pragma unroll
      for (int k = 0; k < 4; ++k) {
        av[k] = sv[tid * 4 + k];               ai[k] = si[tid * 4 + k];
        bv2[k] = sv[(tid + stride) * 4 + k];   bi2[k] = si[(tid + stride) * 4 + k];
      }
      float ov[4]; int oi[4]; int pa = 0, pb = 0;
      #pragma unroll
      for (int k = 0; k < 4; ++k) {
        bool takeA = (pa < 4) && (pb >= 4 || better(av[pa], ai[pa], bv2[pb], bi2[pb]));
        if (takeA) { ov[k] = av[pa]; oi[k] = ai[pa]; ++pa; }
        else       { ov[k] = bv2[pb]; oi[k] = bi2[pb]; ++pb; }
      }
      #pragma unroll
      for (int k = 0; k < 4; ++k) { sv[tid * 4 + k] = ov[k]; si[tid * 4 + k] = oi[k]; }
    }
  }
  __syncthreads();
  const float tau = sv[3] - TOPK_DELTA;

  // collect candidates within the window
  for (int e4 = tid * 4; e4 < E_DIM; e4 += 1024) {
    #pragma unroll
    for (int j = 0; j < 4; ++j) {
      int e = e4 + j;
      if (scores[e] >= tau) {
        int pos = atomicAdd(&cnt, 1);
        if (pos < MAXCAND) candIdx[pos] = e;
      }
    }
  }
  __syncthreads();
  int cntc = min(cnt, MAXCAND);

  // exact fp32 evaluation: one wave per candidate
  const float* R = tf + ((size_t)(b * 8) * P_DIM + ref_perm[r]) * D_DIM;
  const int wave = tid >> 6;
  const int lane = tid & 63;
  for (int c = wave; c < cntc; c += 4) {
    int e = candIdx[c];
    const float* E = tf + ((size_t)(b * 8 + 1 + 2 * (e >> 11)) * P_DIM + (e & (P_DIM - 1))) * D_DIM;
    float d = 0.0f, n2 = 0.0f;
    #pragma unroll
    for (int i = 0; i < 4; ++i) {
      float4 rv = *(const float4*)(R + lane * 16 + i * 4);
      float4 ev = *(const float4*)(E + lane * 16 + i * 4);
      d += dot4(rv, ev);
      n2 += dot4(ev, ev);
    }
    #pragma unroll
    for (int o = 32; o > 0; o >>= 1) { d += __shfl_xor(d, o); n2 += __shfl_xor(n2, o); }
    if (lane == 0) candVal[c] = d / fmaxf(sqrtf(n2), 1e-12f);
  }
  __syncthreads();
  if (tid == 0) {
    float bv[4] = {-FLT_MAX, -FLT_MAX, -FLT_MAX, -FLT_MAX};
    int bi[4] = {INT_MAX, INT_MAX, INT_MAX, INT_MAX};
    for (int c = 0; c < cntc; ++c) {
      float x = candVal[c]; int e = candIdx[c];
      if (better(x, e, bv[3], bi[3])) {
        bv[3] = x; bi[3] = e;
        #pragma unroll
        for (int k = 3; k > 0; --k) {
          if (better(bv[k], bi[k], bv[k - 1], bi[k - 1])) {
            float fv = bv[k]; bv[k] = bv[k - 1]; bv[k - 1] = fv;
            int fi2 = bi[k]; bi[k] = bi[k - 1]; bi[k - 1] = fi2;
          }
        }
      }
    }
    #pragma unroll
    for (int k = 0; k < 4; ++k) tki[br * 4 + k] = bi[k];
  }
}

// ---------- per-(b,r) tables: Rn2(t/s), Hn2, RH(t/s) ----------
__global__ __launch_bounds__(256) void tables_kernel(const float* __restrict__ tf,
                                                     const float* __restrict__ sf,
                                                     const int* __restrict__ ref_perm,
                                                     const int* __restrict__ tki,
                                                     float* __restrict__ rt_n2, float* __restrict__ rs_n2,
                                                     float* __restrict__ hn2,
                                                     float* __restrict__ rh_t, float* __restrict__ rh_s) {
  __shared__ float scr[4];
  int br = blockIdx.x;
  int b = br >> 7, r = br & 127;
  const float* rt = tf + ((size_t)(b * 8) * P_DIM + ref_perm[r]) * D_DIM;
  const float* rs = sf + ((size_t)(b * 4) * P_DIM + ref_perm[r]) * D_DIM;
  int j = threadIdx.x * 4;
  float4 vt = *(const float4*)(rt + j);
  float4 vs = *(const float4*)(rs + j);
  float red;
  red = block_reduce_sum(dot4(vt, vt), scr); if (threadIdx.x == 0) rt_n2[br] = red;
  red = block_reduce_sum(dot4(vs, vs), scr); if (threadIdx.x == 0) rs_n2[br] = red;
  for (int k = 0; k < KTOP; ++k) {
    int e = tki[br * KTOP + k];
    const float* hp = tf + ((size_t)(b * 8 + 1 + 2 * (e >> 11)) * P_DIM + (e & (P_DIM - 1))) * D_DIM;
    float4 vh = *(const float4*)(hp + j);
    red = block_reduce_sum(dot4(vh, vh), scr); if (threadIdx.x == 0) hn2[br * KTOP + k] = red;
    red = block_reduce_sum(dot4(vt, vh), scr); if (threadIdx.x == 0) rh_t[br * KTOP + k] = red;
    red = block_reduce_sum(dot4(vs, vh), scr); if (threadIdx.x == 0) rh_s[br * KTOP + k] = red;
  }
}

// ---------- Sh norms for 3 pairs, both sides ----------
__global__ __launch_bounds__(256) void sh_norms_kernel(const float* __restrict__ tf,
                                                       const float* __restrict__ sf,
                                                       const int* __restrict__ shared_perm,
                                                       float* __restrict__ shn2_t,
                                                       float* __restrict__ shn2_s) {
  __shared__ float scr[4];
  int row = blockIdx.x;                 // ((p*2 + b)*2 + side)*128 + s
  int s = row & 127;
  int side = (row >> 7) & 1;
  int b = (row >> 8) & 1;
  int p = row >> 9;
  const float* ptr = (side == 0)
      ? tf + ((size_t)(b * 8 + 2 * p + 2) * P_DIM + shared_perm[s]) * D_DIM
      : sf + ((size_t)(b * 4 + p + 1) * P_DIM + shared_perm[s]) * D_DIM;
  float4 v = *(const float4*)(ptr + threadIdx.x * 4);
  float red = block_reduce_sum(dot4(v, v), scr);
  if (threadIdx.x == 0) {
    float* dst = (side == 0) ? shn2_t : shn2_s;
    dst[(p * 2 + b) * NS + s] = red;
  }
}

// ============ pair GEMM: 128(M)x64(N) tile, 8x4 micro, split-K 4 (fp32, unchanged from R4) ============
__global__ __launch_bounds__(256) void pair_gemm_kernel(const float* __restrict__ tf,
                                                        const float* __restrict__ sf,
                                                        const int* __restrict__ ref_perm,
                                                        const int* __restrict__ shared_perm,
                                                        const int* __restrict__ tki,
                                                        float* __restrict__ CpP) {
  __shared__ float As[2][16][128];
  __shared__ float Bs[2][16][68];
  __shared__ const float* Arow[128];
  __shared__ const float* Brow[64];
  const int tid = threadIdx.x;
  const int b = blockIdx.z & 1;
  const int slice = blockIdx.z >> 1;
  const int mbase = blockIdx.y * 128;
  const int nbase = blockIdx.x * 64;
  const int kbase = slice * PAIR_KSLICE;
  if (tid < 128) {
    int m = mbase + tid;
    const float* p;
    if (m < 128) {
      p = tf + ((size_t)(b * 8) * P_DIM + ref_perm[m]) * D_DIM;
    } else if (m < 256) {
      p = sf + ((size_t)(b * 4) * P_DIM + ref_perm[m - 128]) * D_DIM;
    } else {
      int h = m - 256, r = h >> 2, k = h & 3;
      int e = tki[(b * NR + r) * KTOP + k];
      p = tf + ((size_t)(b * 8 + 1 + 2 * (e >> 11)) * P_DIM + (e & (P_DIM - 1))) * D_DIM;
    }
    Arow[tid] = p + kbase;
  } else if (tid < 192) {
    int n = nbase + (tid - 128);
    int pr = n >> 8, rem = n & 255, side = rem >> 7, s = rem & 127;
    const float* p;
    if (side == 0) p = tf + ((size_t)(b * 8 + 2 * pr + 2) * P_DIM + shared_perm[s]) * D_DIM;
    else           p = sf + ((size_t)(b * 4 + pr + 1) * P_DIM + shared_perm[s]) * D_DIM;
    Brow[tid - 128] = p + kbase;
  }
  __syncthreads();
  const int rowA = tid & 127;
  const int h8   = (tid >> 7) * 8;
  const int rowB = tid >> 2;
  const int lfB  = (tid & 3) * 4;
  const float* ap = Arow[rowA] + h8;
  const float* bp = Brow[rowB] + lfB;
  float4 a0 = *(const float4*)(ap);
  float4 a1 = *(const float4*)(ap + 4);
  float4 b0 = *(const float4*)(bp);

#define STASH(BUF) do { \
    As[BUF][h8 + 0][rowA] = a0.x; As[BUF][h8 + 1][rowA] = a0.y; \
    As[BUF][h8 + 2][rowA] = a0.z; As[BUF][h8 + 3][rowA] = a0.w; \
    As[BUF][h8 + 4][rowA] = a1.x; As[BUF][h8 + 5][rowA] = a1.y; \
    As[BUF][h8 + 6][rowA] = a1.z; As[BUF][h8 + 7][rowA] = a1.w; \
    Bs[BUF][lfB + 0][rowB] = b0.x; Bs[BUF][lfB + 1][rowB] = b0.y; \
    Bs[BUF][lfB + 2][rowB] = b0.z; Bs[BUF][lfB + 3][rowB] = b0.w; \
  } while (0)

  STASH(0);
  __syncthreads();

  const int tm8 = (tid >> 4) * 8;
  const int tn4 = (tid & 15) * 4;
  float acc[8][4] = {};
  for (int s = 0; s < PAIR_STAGES; ++s) {
    const int cur = s & 1;
    const bool more = (s + 1 < PAIR_STAGES);
    if (more) {
      ap += 16; bp += 16;
      a0 = *(const float4*)(ap);
      a1 = *(const float4*)(ap + 4);
      b0 = *(const float4*)(bp);
    }
    #pragma unroll
    for (int kk = 0; kk < 16; ++kk) {
      float4 x0 = *(const float4*)&As[cur][kk][tm8];
      float4 x1 = *(const float4*)&As[cur][kk][tm8 + 4];
      float4 y0 = *(const float4*)&Bs[cur][kk][tn4];
      float av[8] = {x0.x, x0.y, x0.z, x0.w, x1.x, x1.y, x1.z, x1.w};
      float bv[4] = {y0.x, y0.y, y0.z, y0.w};
      #pragma unroll
      for (int i = 0; i < 8; ++i)
        #pragma unroll
        for (int j = 0; j < 4; ++j)
          acc[i][j] = fmaf(av[i], bv[j], acc[i][j]);
    }
    if (more) STASH(cur ^ 1);
    __syncthreads();
  }

  float* base = CpP + (((size_t)slice * NB + b) * M_PAIR + mbase) * N_PAIR + nbase;
  #pragma unroll
  for (int i = 0; i < 8; ++i) {
    float4 o = make_float4(acc[i][0], acc[i][1], acc[i][2], acc[i][3]);
    *(float4*)(base + (size_t)(tm8 + i) * N_PAIR + tn4) = o;
  }
#undef STASH
}

// ---------- angle + Huber reduction (sums pair split-K partials inline) ----------
__global__ __launch_bounds__(128) void loss_kernel(const float* __restrict__ CpP,
                                                   const float* __restrict__ rt_n2,
                                                   const float* __restrict__ rs_n2,
                                                   const float* __restrict__ hn2,
                                                   const float* __restrict__ rh_t,
                                                   const float* __restrict__ rh_s,
                                                   const float* __restrict__ shn2_t,
                                                   const float* __restrict__ shn2_s,
                                                   float* __restrict__ acc) {
  __shared__ float scr[2];
  int r = blockIdx.x, b = blockIdx.y, p = blockIdx.z;
  int s = threadIdx.x;
  int br = b * NR + r;
  const size_t SLC = (size_t)NB * M_PAIR * N_PAIR;
  const float* Cb = CpP + (size_t)b * M_PAIR * N_PAIR;
  auto sumC = [&](int m, int n) -> float {
    const float* q = Cb + (size_t)m * N_PAIR + n;
    float v = 0.0f;
    #pragma unroll
    for (int sl = 0; sl < PAIR_SLICES; ++sl) v += q[sl * SLC];
    return v;
  };
  float Rt2 = rt_n2[br], Rs2 = rs_n2[br];
  float St2 = shn2_t[(p * 2 + b) * NS + s];
  float Ss2 = shn2_s[(p * 2 + b) * NS + s];
  float RSt = sumC(r, p * 256 + s);
  float RSs = sumC(128 + r, p * 256 + 128 + s);
  float sum = 0.0f;
  #pragma unroll
  for (int k = 0; k < KTOP; ++k) {
    float H2 = hn2[br * KTOP + k];
    float RHt = rh_t[br * KTOP + k];
    float RHs = rh_s[br * KTOP + k];
    float HSt = sumC(256 + r * 4 + k, p * 256 + s);
    float HSs = sumC(256 + r * 4 + k, p * 256 + 128 + s);
    float nRSt = fmaxf(sqrtf(fmaxf(Rt2 + St2 - 2.0f * RSt, 0.0f)), ANG_EPS);
    float nRHt = fmaxf(sqrtf(fmaxf(Rt2 + H2 - 2.0f * RHt, 0.0f)), ANG_EPS);
    float nHSt = fmaxf(sqrtf(fmaxf(H2 + St2 - 2.0f * HSt, 0.0f)), ANG_EPS);
    float a1t = (HSt - RSt - RHt + Rt2) / (nRSt * nRHt);
    float a2t = (RSt - RHt - HSt + H2) / (nRHt * nHSt);
    float a3t = (RHt - RSt - HSt + St2) / (nRSt * nHSt);
    float nRSs = fmaxf(sqrtf(fmaxf(Rs2 + Ss2 - 2.0f * RSs, 0.0f)), ANG_EPS);
    float nRHs = fmaxf(sqrtf(fmaxf(Rs2 + H2 - 2.0f * RHs, 0.0f)), ANG_EPS);
    float nHSs = fmaxf(sqrtf(fmaxf(H2 + Ss2 - 2.0f * HSs, 0.0f)), ANG_EPS);
    float a1s = (HSs - RSs - RHs + Rs2) / (nRSs * nRHs);
    float a2s = (RSs - RHs - HSs + H2) / (nRHs * nHSs);
    float a3s = (RHs - RSs - HSs + Ss2) / (nRSs * nHSs);
    sum += huber(a1s - a1t) + huber(a2s - a2t) + huber(a3s - a3t);
  }
  float tot = block_reduce_sum(sum, scr);
  if (threadIdx.x == 0) atomicAdd(acc, tot);
}

__global__ void finalize_kernel(const float* __restrict__ acc, float* __restrict__ out) {
  if (threadIdx.x == 0 && blockIdx.x == 0)
    out[0] = acc[0] * (1.0f / 393216.0f);   // 3 * B * NR * NS * KTOP
}

extern "C" void kernel_launch(void* const* d_in, const int* in_sizes, int n_in,
                              void* d_out, int out_size, void* d_ws, size_t ws_size,
                              hipStream_t stream) {
  const float* tf = (const float*)d_in[0];
  const float* sf = (const float*)d_in[1];
  const int* ref_perm = (const int*)d_in[2];
  const int* shared_perm = (const int*)d_in[3];
  float* ws = (float*)d_ws;

  float* simP   = ws;                                          // 4*2*128*8192
  float* bn2P   = simP + (size_t)SIM_SLICES * NB * NR * E_DIM; // 4*2*8192
  float* CpP    = bn2P + (size_t)SIM_SLICES * NB * E_DIM;      // 4*2*768*768
  float* rt_n2  = CpP  + (size_t)PAIR_SLICES * NB * M_PAIR * N_PAIR;
  float* rs_n2  = rt_n2  + NB * NR;
  float* hn2    = rs_n2  + NB * NR;
  float* rh_t   = hn2    + NB * NR * KTOP;
  float* rh_s   = rh_t   + NB * NR * KTOP;
  float* shn2_t = rh_s   + NB * NR * KTOP;
  float* shn2_s = shn2_t + 3 * NB * NS;
  float* acc    = shn2_s + 3 * NB * NS;
  int*   tki    = (int*)(acc + 4);
  float* out = (float*)d_out;

  hipMemsetAsync(acc, 0, sizeof(float), stream);
  sim_gemm_kernel<<<dim3(E_DIM / 128, SIM_SLICES, NB), 256, 0, stream>>>(tf, ref_perm, simP, bn2P);
  topk_kernel<<<NB * NR, 256, 0, stream>>>(simP, bn2P, tf, ref_perm, tki);
  tables_kernel<<<NB * NR, 256, 0, stream>>>(tf, sf, ref_perm, tki, rt_n2, rs_n2, hn2, rh_t, rh_s);
  sh_norms_kernel<<<3 * NB * 2 * NS, 256, 0, stream>>>(tf, sf, shared_perm, shn2_t, shn2_s);
  pair_gemm_kernel<<<dim3(N_PAIR / 64, M_PAIR / 128, NB * PAIR_SLICES), 256, 0, stream>>>(tf, sf, ref_perm, shared_perm, tki, CpP);
  loss_kernel<<<dim3(NR, NB, 3), 128, 0, stream>>>(CpP, rt_n2, rs_n2, hn2, rh_t, rh_s, shn2_t, shn2_s, acc);
  finalize_kernel<<<1, 64, 0, stream>>>(acc, out);
}

// Round 6
// 281.373 us; speedup vs baseline: 1.2209x; 1.2209x over previous
//
#include <hip/hip_runtime.h>
#include <cstdint>
#include <cstddef>
#include <cfloat>
#include <climits>

#define D_DIM   1024
#define P_DIM   2048
#define NB      2
#define NR      128
#define NS      128
#define KTOP    4
#define E_DIM   8192
#define ANG_EPS 1e-8f
#define M_PAIR  768   // 128 ref_t + 128 ref_s + 512 H rows
#define N_PAIR  768   // 3 pairs * (128 Sh_t + 128 Sh_s)

#define SIM_SLICES  4
#define SIM_KSLICE  256     // 8 chunks of 32
#define PAIR_SLICES 8
#define PAIR_KSLICE 128     // 4 chunks of 32

#define TOPK_DELTA  0.25f   // ~150 sigma of bf16 score error (0.0016)
#define MAXCAND     128

typedef short short8 __attribute__((ext_vector_type(8)));
typedef float f32x4 __attribute__((ext_vector_type(4)));

__device__ __forceinline__ float dot4(float4 a, float4 b) {
  return a.x * b.x + a.y * b.y + a.z * b.z + a.w * b.w;
}

__device__ __forceinline__ float huber(float e) {
  float ae = fabsf(e);
  return ae <= 1.0f ? 0.5f * e * e : ae - 0.5f;
}

__device__ __forceinline__ bool better(float va, int ia, float vb, int ib) {
  return (va > vb) || (va == vb && ia < ib);
}

// RNE float -> bf16 bits
__device__ __forceinline__ unsigned int f2bf(float x) {
  union { float f; unsigned int u; } v; v.f = x;
  unsigned int r = v.u + 0x7fffu + ((v.u >> 16) & 1u);
  return r >> 16;
}
__device__ __forceinline__ unsigned int pk2bf(float x, float y) {
  return f2bf(x) | (f2bf(y) << 16);
}

// valid result on thread 0 only; scratch must hold blockDim/64 floats
__device__ __forceinline__ float block_reduce_sum(float v, float* scratch) {
  #pragma unroll
  for (int o = 32; o > 0; o >>= 1) v += __shfl_down(v, o);
  __syncthreads();
  if ((threadIdx.x & 63) == 0) scratch[threadIdx.x >> 6] = v;
  __syncthreads();
  float r = 0.0f;
  int nw = (int)(blockDim.x >> 6);
  if ((int)threadIdx.x < nw) r = scratch[threadIdx.x];
  #pragma unroll
  for (int o = 2; o > 0; o >>= 1) r += __shfl_down(r, o);
  return r;
}

// ============ sim GEMM via bf16 MFMA: 128x128 tile, split-K 4, fused fp32 norms ============
__global__ __launch_bounds__(256) void sim_gemm_kernel(const float* __restrict__ tf,
                                                       const int* __restrict__ ref_perm,
                                                       float* __restrict__ simP,
                                                       float* __restrict__ bn2P) {
  __shared__ unsigned int Ah[128 * 20];   // 128 rows x 40 bf16 (32 used + pad) = 80 B/row
  __shared__ unsigned int Bh[128 * 20];
  __shared__ const float* Arow[128];
  __shared__ const float* Brow[128];
  const int tid = threadIdx.x;
  const int b = blockIdx.z;
  const int slice = blockIdx.y;
  const int nbase = blockIdx.x * 128;
  const int kbase = slice * SIM_KSLICE;
  if (tid < 128) {
    Arow[tid] = tf + ((size_t)(b * 8) * P_DIM + ref_perm[tid]) * D_DIM + kbase;
  } else {
    int n = nbase + (tid - 128);
    Brow[tid - 128] = tf + ((size_t)(b * 8 + 1 + 2 * (n >> 11)) * P_DIM + (n & (P_DIM - 1))) * D_DIM + kbase;
  }
  __syncthreads();

  const int srow = tid >> 1;          // staging row 0..127
  const int shalf = (tid & 1) * 16;   // k-offset 0 or 16
  const float* asrc = Arow[srow] + shalf;
  const float* bsrc = Brow[srow] + shalf;

  float4 av[4], bv[4];
  #pragma unroll
  for (int i = 0; i < 4; ++i) {
    av[i] = *(const float4*)(asrc + 4 * i);
    bv[i] = *(const float4*)(bsrc + 4 * i);
  }

  const int wave = tid >> 6;
  const int lane = tid & 63;
  const int fr = lane & 15;
  const int q16 = (lane >> 4) * 16;   // byte offset of k-group
  const char* Ab = (const char*)Ah;
  const char* Bb = (const char*)Bh;

  f32x4 acc[2][8];
  #pragma unroll
  for (int mt = 0; mt < 2; ++mt)
    #pragma unroll
    for (int nt = 0; nt < 8; ++nt)
      #pragma unroll
      for (int r = 0; r < 4; ++r) acc[mt][nt][r] = 0.0f;

  float bn2 = 0.0f;
  unsigned int* adst = Ah + srow * 20 + (tid & 1) * 8;
  unsigned int* bdst = Bh + srow * 20 + (tid & 1) * 8;

  for (int ck = 0; ck < 8; ++ck) {
    bn2 += dot4(bv[0], bv[0]) + dot4(bv[1], bv[1]) + dot4(bv[2], bv[2]) + dot4(bv[3], bv[3]);
    unsigned int ua[8], ub[8];
    #pragma unroll
    for (int i = 0; i < 4; ++i) {
      ua[2 * i]     = pk2bf(av[i].x, av[i].y);
      ua[2 * i + 1] = pk2bf(av[i].z, av[i].w);
      ub[2 * i]     = pk2bf(bv[i].x, bv[i].y);
      ub[2 * i + 1] = pk2bf(bv[i].z, bv[i].w);
    }
    __syncthreads();
    *(uint4*)(adst)     = make_uint4(ua[0], ua[1], ua[2], ua[3]);
    *(uint4*)(adst + 4) = make_uint4(ua[4], ua[5], ua[6], ua[7]);
    *(uint4*)(bdst)     = make_uint4(ub[0], ub[1], ub[2], ub[3]);
    *(uint4*)(bdst + 4) = make_uint4(ub[4], ub[5], ub[6], ub[7]);
    __syncthreads();
    if (ck < 7) {
      const float* an = asrc + (ck + 1) * 32;
      const float* bn = bsrc + (ck + 1) * 32;
      #pragma unroll
      for (int i = 0; i < 4; ++i) {
        av[i] = *(const float4*)(an + 4 * i);
        bv[i] = *(const float4*)(bn + 4 * i);
      }
    }
    short8 afr[2], bfr[8];
    #pragma unroll
    for (int mt = 0; mt < 2; ++mt)
      afr[mt] = *(const short8*)(Ab + (wave * 32 + mt * 16 + fr) * 80 + q16);
    #pragma unroll
    for (int nt = 0; nt < 8; ++nt)
      bfr[nt] = *(const short8*)(Bb + (nt * 16 + fr) * 80 + q16);
    #pragma unroll
    for (int mt = 0; mt < 2; ++mt)
      #pragma unroll
      for (int nt = 0; nt < 8; ++nt)
        acc[mt][nt] = __builtin_amdgcn_mfma_f32_16x16x32_bf16(afr[mt], bfr[nt], acc[mt][nt], 0, 0, 0);
  }

  bn2 += __shfl_xor(bn2, 1);
  if ((tid & 1) == 0)
    bn2P[((size_t)slice * NB + b) * E_DIM + nbase + srow] = bn2;

  // C/D layout: col = lane&15, row = (lane>>4)*4 + reg
  float* base = simP + (((size_t)slice * NB + b) * NR) * E_DIM + nbase;
  const int crow = (lane >> 4) * 4;
  #pragma unroll
  for (int mt = 0; mt < 2; ++mt) {
    #pragma unroll
    for (int nt = 0; nt < 8; ++nt) {
      int col = nt * 16 + fr;
      #pragma unroll
      for (int r = 0; r < 4; ++r) {
        int m = wave * 32 + mt * 16 + crow + r;
        base[(size_t)m * E_DIM + col] = acc[mt][nt][r];
      }
    }
  }
}

// ---------- top-4 per row (approx -> exact recheck) + fused per-(b,r) tables ----------
__global__ __launch_bounds__(256) void topk_kernel(const float* __restrict__ simP,
                                                   const float* __restrict__ bn2P,
                                                   const float* __restrict__ tf,
                                                   const float* __restrict__ sf,
                                                   const int* __restrict__ ref_perm,
                                                   int* __restrict__ tki,
                                                   float* __restrict__ rt_n2,
                                                   float* __restrict__ rs_n2,
                                                   float* __restrict__ hn2,
                                                   float* __restrict__ rh_t,
                                                   float* __restrict__ rh_s) {
  __shared__ float scores[E_DIM];       // 32 KB
  __shared__ float sv[1024];
  __shared__ int si[1024];
  __shared__ float candVal[MAXCAND];
  __shared__ int candIdx[MAXCAND];
  __shared__ int cnt;
  __shared__ int fin4[4];
  const int tid = threadIdx.x;
  const int br = blockIdx.x;
  const int b = br >> 7;
  const int r = br & 127;
  const size_t ST = (size_t)NB * NR * E_DIM;
  const size_t SN = (size_t)NB * E_DIM;
  const float* p = simP + (size_t)br * E_DIM;
  const float* q = bn2P + (size_t)b * E_DIM;
  if (tid == 0) cnt = 0;

  float tv[4] = {-FLT_MAX, -FLT_MAX, -FLT_MAX, -FLT_MAX};
  int ti[4] = {INT_MAX, INT_MAX, INT_MAX, INT_MAX};
  for (int e4 = tid * 4; e4 < E_DIM; e4 += 1024) {
    float4 s = *(const float4*)(p + e4);
    float4 s1 = *(const float4*)(p + ST + e4);
    float4 s2 = *(const float4*)(p + 2 * ST + e4);
    float4 s3 = *(const float4*)(p + 3 * ST + e4);
    float4 n0 = *(const float4*)(q + e4);
    float4 n1 = *(const float4*)(q + SN + e4);
    float4 n2 = *(const float4*)(q + 2 * SN + e4);
    float4 n3 = *(const float4*)(q + 3 * SN + e4);
    float sj[4] = {s.x + s1.x + s2.x + s3.x, s.y + s1.y + s2.y + s3.y,
                   s.z + s1.z + s2.z + s3.z, s.w + s1.w + s2.w + s3.w};
    float nj[4] = {n0.x + n1.x + n2.x + n3.x, n0.y + n1.y + n2.y + n3.y,
                   n0.z + n1.z + n2.z + n3.z, n0.w + n1.w + n2.w + n3.w};
    #pragma unroll
    for (int j = 0; j < 4; ++j) {
      int e = e4 + j;
      float x = sj[j] * rsqrtf(fmaxf(nj[j], 1e-24f));
      scores[e] = x;
      if (better(x, e, tv[3], ti[3])) {
        tv[3] = x; ti[3] = e;
        #pragma unroll
        for (int k = 3; k > 0; --k) {
          if (better(tv[k], ti[k], tv[k - 1], ti[k - 1])) {
            float fv = tv[k]; tv[k] = tv[k - 1]; tv[k - 1] = fv;
            int fi2 = ti[k]; ti[k] = ti[k - 1]; ti[k - 1] = fi2;
          }
        }
      }
    }
  }
  #pragma unroll
  for (int k = 0; k < 4; ++k) { sv[tid * 4 + k] = tv[k]; si[tid * 4 + k] = ti[k]; }
  for (int stride = 128; stride > 0; stride >>= 1) {
    __syncthreads();
    if (tid < stride) {
      float av[4], bv2[4]; int ai[4], bi2[4];
      #pragma unroll
      for (int k = 0; k < 4; ++k) {
        av[k] = sv[tid * 4 + k];               ai[k] = si[tid * 4 + k];
        bv2[k] = sv[(tid + stride) * 4 + k];   bi2[k] = si[(tid + stride) * 4 + k];
      }
      float ov[4]; int oi[4]; int pa = 0, pb = 0;
      #pragma unroll
      for (int k = 0; k < 4; ++k) {
        bool takeA = (pa < 4) && (pb >= 4 || better(av[pa], ai[pa], bv2[pb], bi2[pb]));
        if (takeA) { ov[k] = av[pa]; oi[k] = ai[pa]; ++pa; }
        else       { ov[k] = bv2[pb]; oi[k] = bi2[pb]; ++pb; }
      }
      #pragma unroll
      for (int k = 0; k < 4; ++k) { sv[tid * 4 + k] = ov[k]; si[tid * 4 + k] = oi[k]; }
    }
  }
  __syncthreads();
  const float tau = sv[3] - TOPK_DELTA;

  for (int e4 = tid * 4; e4 < E_DIM; e4 += 1024) {
    #pragma unroll
    for (int j = 0; j < 4; ++j) {
      int e = e4 + j;
      if (scores[e] >= tau) {
        int pos = atomicAdd(&cnt, 1);
        if (pos < MAXCAND) candIdx[pos] = e;
      }
    }
  }
  __syncthreads();
  int cntc = min(cnt, MAXCAND);

  // exact fp32 evaluation: one wave per candidate
  const float* R = tf + ((size_t)(b * 8) * P_DIM + ref_perm[r]) * D_DIM;
  const int wave = tid >> 6;
  const int lane = tid & 63;
  for (int c = wave; c < cntc; c += 4) {
    int e = candIdx[c];
    const float* E = tf + ((size_t)(b * 8 + 1 + 2 * (e >> 11)) * P_DIM + (e & (P_DIM - 1))) * D_DIM;
    float d = 0.0f, n2 = 0.0f;
    #pragma unroll
    for (int i = 0; i < 4; ++i) {
      float4 rv = *(const float4*)(R + lane * 16 + i * 4);
      float4 ev = *(const float4*)(E + lane * 16 + i * 4);
      d += dot4(rv, ev);
      n2 += dot4(ev, ev);
    }
    #pragma unroll
    for (int o = 32; o > 0; o >>= 1) { d += __shfl_xor(d, o); n2 += __shfl_xor(n2, o); }
    if (lane == 0) candVal[c] = d / fmaxf(sqrtf(n2), 1e-12f);
  }
  __syncthreads();
  if (tid == 0) {
    float bv[4] = {-FLT_MAX, -FLT_MAX, -FLT_MAX, -FLT_MAX};
    int bi[4] = {INT_MAX, INT_MAX, INT_MAX, INT_MAX};
    for (int c = 0; c < cntc; ++c) {
      float x = candVal[c]; int e = candIdx[c];
      if (better(x, e, bv[3], bi[3])) {
        bv[3] = x; bi[3] = e;
        #pragma unroll
        for (int k = 3; k > 0; --k) {
          if (better(bv[k], bi[k], bv[k - 1], bi[k - 1])) {
            float fv = bv[k]; bv[k] = bv[k - 1]; bv[k - 1] = fv;
            int fi2 = bi[k]; bi[k] = bi[k - 1]; bi[k - 1] = fi2;
          }
        }
      }
    }
    #pragma unroll
    for (int k = 0; k < 4; ++k) { tki[br * 4 + k] = bi[k]; fin4[k] = bi[k]; }
  }
  __syncthreads();

  // ----- fused tables: wave w handles H_w; also Rn2 (wave0: teacher, wave1: student) -----
  {
    const float* RS = sf + ((size_t)(b * 4) * P_DIM + ref_perm[r]) * D_DIM;
    int e = fin4[wave];
    const float* H = tf + ((size_t)(b * 8 + 1 + 2 * (e >> 11)) * P_DIM + (e & (P_DIM - 1))) * D_DIM;
    float h2 = 0.0f, rht = 0.0f, rhs = 0.0f, rtn = 0.0f, rsn = 0.0f;
    #pragma unroll
    for (int i = 0; i < 4; ++i) {
      float4 rv = *(const float4*)(R + lane * 16 + i * 4);
      float4 sv2 = *(const float4*)(RS + lane * 16 + i * 4);
      float4 hv = *(const float4*)(H + lane * 16 + i * 4);
      h2 += dot4(hv, hv);
      rht += dot4(rv, hv);
      rhs += dot4(sv2, hv);
      rtn += dot4(rv, rv);
      rsn += dot4(sv2, sv2);
    }
    #pragma unroll
    for (int o = 32; o > 0; o >>= 1) {
      h2 += __shfl_xor(h2, o);
      rht += __shfl_xor(rht, o);
      rhs += __shfl_xor(rhs, o);
      rtn += __shfl_xor(rtn, o);
      rsn += __shfl_xor(rsn, o);
    }
    if (lane == 0) {
      hn2[br * KTOP + wave] = h2;
      rh_t[br * KTOP + wave] = rht;
      rh_s[br * KTOP + wave] = rhs;
      if (wave == 0) rt_n2[br] = rtn;
      if (wave == 1) rs_n2[br] = rsn;
    }
  }
}

// ---------- Sh norms for 3 pairs, both sides ----------
__global__ __launch_bounds__(256) void sh_norms_kernel(const float* __restrict__ tf,
                                                       const float* __restrict__ sf,
                                                       const int* __restrict__ shared_perm,
                                                       float* __restrict__ shn2_t,
                                                       float* __restrict__ shn2_s) {
  __shared__ float scr[4];
  int row = blockIdx.x;                 // ((p*2 + b)*2 + side)*128 + s
  int s = row & 127;
  int side = (row >> 7) & 1;
  int b = (row >> 8) & 1;
  int p = row >> 9;
  const float* ptr = (side == 0)
      ? tf + ((size_t)(b * 8 + 2 * p + 2) * P_DIM + shared_perm[s]) * D_DIM
      : sf + ((size_t)(b * 4 + p + 1) * P_DIM + shared_perm[s]) * D_DIM;
  float4 v = *(const float4*)(ptr + threadIdx.x * 4);
  float red = block_reduce_sum(dot4(v, v), scr);
  if (threadIdx.x == 0) {
    float* dst = (side == 0) ? shn2_t : shn2_s;
    dst[(p * 2 + b) * NS + s] = red;
  }
}

// ============ pair GEMM via bf16 MFMA: 128x128 tile, split-K 8 ============
__global__ __launch_bounds__(256) void pair_gemm_kernel(const float* __restrict__ tf,
                                                        const float* __restrict__ sf,
                                                        const int* __restrict__ ref_perm,
                                                        const int* __restrict__ shared_perm,
                                                        const int* __restrict__ tki,
                                                        float* __restrict__ CpP) {
  __shared__ unsigned int Ah[128 * 20];
  __shared__ unsigned int Bh[128 * 20];
  __shared__ const float* Arow[128];
  __shared__ const float* Brow[128];
  const int tid = threadIdx.x;
  const int b = blockIdx.z & 1;
  const int slice = blockIdx.z >> 1;
  const int mbase = blockIdx.y * 128;
  const int nbase = blockIdx.x * 128;
  const int kbase = slice * PAIR_KSLICE;
  if (tid < 128) {
    int m = mbase + tid;
    const float* p;
    if (m < 128) {
      p = tf + ((size_t)(b * 8) * P_DIM + ref_perm[m]) * D_DIM;
    } else if (m < 256) {
      p = sf + ((size_t)(b * 4) * P_DIM + ref_perm[m - 128]) * D_DIM;
    } else {
      int h = m - 256, r = h >> 2, k = h & 3;
      int e = tki[(b * NR + r) * KTOP + k];
      p = tf + ((size_t)(b * 8 + 1 + 2 * (e >> 11)) * P_DIM + (e & (P_DIM - 1))) * D_DIM;
    }
    Arow[tid] = p + kbase;
  } else {
    int n = nbase + (tid - 128);
    int pr = n >> 8, rem = n & 255, side = rem >> 7, s = rem & 127;
    const float* p;
    if (side == 0) p = tf + ((size_t)(b * 8 + 2 * pr + 2) * P_DIM + shared_perm[s]) * D_DIM;
    else           p = sf + ((size_t)(b * 4 + pr + 1) * P_DIM + shared_perm[s]) * D_DIM;
    Brow[tid - 128] = p + kbase;
  }
  __syncthreads();

  const int srow = tid >> 1;
  const int shalf = (tid & 1) * 16;
  const float* asrc = Arow[srow] + shalf;
  const float* bsrc = Brow[srow] + shalf;

  float4 av[4], bv[4];
  #pragma unroll
  for (int i = 0; i < 4; ++i) {
    av[i] = *(const float4*)(asrc + 4 * i);
    bv[i] = *(const float4*)(bsrc + 4 * i);
  }

  const int wave = tid >> 6;
  const int lane = tid & 63;
  const int fr = lane & 15;
  const int q16 = (lane >> 4) * 16;
  const char* Ab = (const char*)Ah;
  const char* Bb = (const char*)Bh;

  f32x4 acc[2][8];
  #pragma unroll
  for (int mt = 0; mt < 2; ++mt)
    #pragma unroll
    for (int nt = 0; nt < 8; ++nt)
      #pragma unroll
      for (int r = 0; r < 4; ++r) acc[mt][nt][r] = 0.0f;

  unsigned int* adst = Ah + srow * 20 + (tid & 1) * 8;
  unsigned int* bdst = Bh + srow * 20 + (tid & 1) * 8;

  for (int ck = 0; ck < 4; ++ck) {
    unsigned int ua[8], ub[8];
    #pragma unroll
    for (int i = 0; i < 4; ++i) {
      ua[2 * i]     = pk2bf(av[i].x, av[i].y);
      ua[2 * i + 1] = pk2bf(av[i].z, av[i].w);
      ub[2 * i]     = pk2bf(bv[i].x, bv[i].y);
      ub[2 * i + 1] = pk2bf(bv[i].z, bv[i].w);
    }
    __syncthreads();
    *(uint4*)(adst)     = make_uint4(ua[0], ua[1], ua[2], ua[3]);
    *(uint4*)(adst + 4) = make_uint4(ua[4], ua[5], ua[6], ua[7]);
    *(uint4*)(bdst)     = make_uint4(ub[0], ub[1], ub[2], ub[3]);
    *(uint4*)(bdst + 4) = make_uint4(ub[4], ub[5], ub[6], ub[7]);
    __syncthreads();
    if (ck < 3) {
      const float* an = asrc + (ck + 1) * 32;
      const float* bn = bsrc + (ck + 1) * 32;
      #pragma unroll
      for (int i = 0; i < 4; ++i) {
        av[i] = *(const float4*)(an + 4 * i);
        bv[i] = *(const float4*)(bn + 4 * i);
      }
    }
    short8 afr[2], bfr[8];
    #pragma unroll
    for (int mt = 0; mt < 2; ++mt)
      afr[mt] = *(const short8*)(Ab + (wave * 32 + mt * 16 + fr) * 80 + q16);
    #pragma unroll
    for (int nt = 0; nt < 8; ++nt)
      bfr[nt] = *(const short8*)(Bb + (nt * 16 + fr) * 80 + q16);
    #pragma unroll
    for (int mt = 0; mt < 2; ++mt)
      #pragma unroll
      for (int nt = 0; nt < 8; ++nt)
        acc[mt][nt] = __builtin_amdgcn_mfma_f32_16x16x32_bf16(afr[mt], bfr[nt], acc[mt][nt], 0, 0, 0);
  }

  float* base = CpP + (((size_t)slice * NB + b) * M_PAIR + mbase) * N_PAIR + nbase;
  const int crow = (lane >> 4) * 4;
  #pragma unroll
  for (int mt = 0; mt < 2; ++mt) {
    #pragma unroll
    for (int nt = 0; nt < 8; ++nt) {
      int col = nt * 16 + fr;
      #pragma unroll
      for (int r = 0; r < 4; ++r) {
        int m = wave * 32 + mt * 16 + crow + r;
        base[(size_t)m * N_PAIR + col] = acc[mt][nt][r];
      }
    }
  }
}

// ---------- angle + Huber reduction (sums pair split-K partials inline) ----------
__global__ __launch_bounds__(128) void loss_kernel(const float* __restrict__ CpP,
                                                   const float* __restrict__ rt_n2,
                                                   const float* __restrict__ rs_n2,
                                                   const float* __restrict__ hn2,
                                                   const float* __restrict__ rh_t,
                                                   const float* __restrict__ rh_s,
                                                   const float* __restrict__ shn2_t,
                                                   const float* __restrict__ shn2_s,
                                                   float* __restrict__ acc) {
  __shared__ float scr[2];
  int r = blockIdx.x, b = blockIdx.y, p = blockIdx.z;
  int s = threadIdx.x;
  int br = b * NR + r;
  const size_t SLC = (size_t)NB * M_PAIR * N_PAIR;
  const float* Cb = CpP + (size_t)b * M_PAIR * N_PAIR;
  auto sumC = [&](int m, int n) -> float {
    const float* q = Cb + (size_t)m * N_PAIR + n;
    float v = 0.0f;
    #pragma unroll
    for (int sl = 0; sl < PAIR_SLICES; ++sl) v += q[sl * SLC];
    return v;
  };
  float Rt2 = rt_n2[br], Rs2 = rs_n2[br];
  float St2 = shn2_t[(p * 2 + b) * NS + s];
  float Ss2 = shn2_s[(p * 2 + b) * NS + s];
  float RSt = sumC(r, p * 256 + s);
  float RSs = sumC(128 + r, p * 256 + 128 + s);
  float sum = 0.0f;
  #pragma unroll
  for (int k = 0; k < KTOP; ++k) {
    float H2 = hn2[br * KTOP + k];
    float RHt = rh_t[br * KTOP + k];
    float RHs = rh_s[br * KTOP + k];
    float HSt = sumC(256 + r * 4 + k, p * 256 + s);
    float HSs = sumC(256 + r * 4 + k, p * 256 + 128 + s);
    float nRSt = fmaxf(sqrtf(fmaxf(Rt2 + St2 - 2.0f * RSt, 0.0f)), ANG_EPS);
    float nRHt = fmaxf(sqrtf(fmaxf(Rt2 + H2 - 2.0f * RHt, 0.0f)), ANG_EPS);
    float nHSt = fmaxf(sqrtf(fmaxf(H2 + St2 - 2.0f * HSt, 0.0f)), ANG_EPS);
    float a1t = (HSt - RSt - RHt + Rt2) / (nRSt * nRHt);
    float a2t = (RSt - RHt - HSt + H2) / (nRHt * nHSt);
    float a3t = (RHt - RSt - HSt + St2) / (nRSt * nHSt);
    float nRSs = fmaxf(sqrtf(fmaxf(Rs2 + Ss2 - 2.0f * RSs, 0.0f)), ANG_EPS);
    float nRHs = fmaxf(sqrtf(fmaxf(Rs2 + H2 - 2.0f * RHs, 0.0f)), ANG_EPS);
    float nHSs = fmaxf(sqrtf(fmaxf(H2 + Ss2 - 2.0f * HSs, 0.0f)), ANG_EPS);
    float a1s = (HSs - RSs - RHs + Rs2) / (nRSs * nRHs);
    float a2s = (RSs - RHs - HSs + H2) / (nRHs * nHSs);
    float a3s = (RHs - RSs - HSs + Ss2) / (nRSs * nHSs);
    sum += huber(a1s - a1t) + huber(a2s - a2t) + huber(a3s - a3t);
  }
  float tot = block_reduce_sum(sum, scr);
  if (threadIdx.x == 0) atomicAdd(acc, tot);
}

__global__ void finalize_kernel(const float* __restrict__ acc, float* __restrict__ out) {
  if (threadIdx.x == 0 && blockIdx.x == 0)
    out[0] = acc[0] * (1.0f / 393216.0f);   // 3 * B * NR * NS * KTOP
}

extern "C" void kernel_launch(void* const* d_in, const int* in_sizes, int n_in,
                              void* d_out, int out_size, void* d_ws, size_t ws_size,
                              hipStream_t stream) {
  const float* tf = (const float*)d_in[0];
  const float* sf = (const float*)d_in[1];
  const int* ref_perm = (const int*)d_in[2];
  const int* shared_perm = (const int*)d_in[3];
  float* ws = (float*)d_ws;

  float* simP   = ws;                                          // 4*2*128*8192
  float* bn2P   = simP + (size_t)SIM_SLICES * NB * NR * E_DIM; // 4*2*8192
  float* CpP    = bn2P + (size_t)SIM_SLICES * NB * E_DIM;      // 8*2*768*768
  float* rt_n2  = CpP  + (size_t)PAIR_SLICES * NB * M_PAIR * N_PAIR;
  float* rs_n2  = rt_n2  + NB * NR;
  float* hn2    = rs_n2  + NB * NR;
  float* rh_t   = hn2    + NB * NR * KTOP;
  float* rh_s   = rh_t   + NB * NR * KTOP;
  float* shn2_t = rh_s   + NB * NR * KTOP;
  float* shn2_s = shn2_t + 3 * NB * NS;
  float* acc    = shn2_s + 3 * NB * NS;
  int*   tki    = (int*)(acc + 4);
  float* out = (float*)d_out;

  hipMemsetAsync(acc, 0, sizeof(float), stream);
  sim_gemm_kernel<<<dim3(E_DIM / 128, SIM_SLICES, NB), 256, 0, stream>>>(tf, ref_perm, simP, bn2P);
  topk_kernel<<<NB * NR, 256, 0, stream>>>(simP, bn2P, tf, sf, ref_perm, tki,
                                           rt_n2, rs_n2, hn2, rh_t, rh_s);
  sh_norms_kernel<<<3 * NB * 2 * NS, 256, 0, stream>>>(tf, sf, shared_perm, shn2_t, shn2_s);
  pair_gemm_kernel<<<dim3(N_PAIR / 128, M_PAIR / 128, NB * PAIR_SLICES), 256, 0, stream>>>(tf, sf, ref_perm, shared_perm, tki, CpP);
  loss_kernel<<<dim3(NR, NB, 3), 128, 0, stream>>>(CpP, rt_n2, rs_n2, hn2, rh_t, rh_s, shn2_t, shn2_s, acc);
  finalize_kernel<<<1, 64, 0, stream>>>(acc, out);
}